// Round 5
// baseline (606.818 us; speedup 1.0000x reference)
//
#include <hip/hip_runtime.h>

// entmax-1.5 attention, round 11: wave-private global_load_lds staging,
// zero barriers in the MFMA loops, counted vmcnt (never drains).
// Insight: wave w only ever reads K rows / V^T rows w*16..w*16+15, so
// staging is WAVE-PRIVATE: global_load_lds into a private LDS slice needs
// no barriers (r7's 64 drain-barriers gone) and no VGPRs (r10's register
// pressure gone). kv[3] rotation = 2-stage lookahead, s_waitcnt vmcnt(4).
// K/V are pre-swizzled IN GLOBAL (gload_lds writes linearly; rule #21) so
// fragment ds_read_b128 stays bank-even. Candidate list overlays sc (row's
// scores are dead after regather; half-wave lockstep -> no race).
// B=4 H=8 S=1024 D=128. LDS = sc 32K + kv 48K = 80 KB -> 2 blocks/CU.
// Stages s=0..31: s<16 K-half (kt=s>>1, dh=s&1), s>=16 V-half (vh=s-16).
// Exactly 2 barriers: scores-visible, y-visible (raw s_barrier + lgkmcnt).

#define S_ 1024
#define D_ 128
#define NEG_INF_F (-1.0e12f)
#define SCALE_F 0.08838834764831845f  // 1/sqrt(128)
#define NITER 14                      // dTau=6e-5 -> out err ~1e-3 << 0.0766
#define CCAP 512                      // cand cap (sc row = 512 f32)

typedef float f32x4 __attribute__((ext_vector_type(4)));
typedef short short8 __attribute__((ext_vector_type(8)));

__device__ __forceinline__ ushort f2bf(float x) {   // RNE f32 -> bf16
    unsigned u = __builtin_bit_cast(unsigned, x);
    u += 0x7FFFu + ((u >> 16) & 1u);
    return (ushort)(u >> 16);
}
__device__ __forceinline__ float bf2f(ushort h) {
    unsigned u = ((unsigned)h) << 16;
    return __builtin_bit_cast(float, u);
}
__device__ __forceinline__ short8 cvt8(float4 a, float4 b) {
    short8 r; ushort* p = (ushort*)&r;
    p[0] = f2bf(a.x); p[1] = f2bf(a.y); p[2] = f2bf(a.z); p[3] = f2bf(a.w);
    p[4] = f2bf(b.x); p[5] = f2bf(b.y); p[6] = f2bf(b.z); p[7] = f2bf(b.w);
    return r;
}
__device__ __forceinline__ void gload16(const ushort* g, ushort* l) {
    __builtin_amdgcn_global_load_lds(
        (const __attribute__((address_space(1))) void*)g,
        (__attribute__((address_space(3))) void*)l, 16, 0, 0);
}

// ---- pre-kernel: K and V -> bf16, SWIZZLED half-tiles ------------------
// Kb layout: [bh][h=kt*2+dh][row=key&127][chunk'=c ^ (row&7)][8]  (d = c*8)
// Vt layout: [bh][vh][drow][chunk'=c ^ (drow&7)][8]               (key = c*8)
__global__ __launch_bounds__(256)
void pre_cvt(const float* __restrict__ K, const float* __restrict__ V,
             ushort* __restrict__ Kb, ushort* __restrict__ Vt)
{
    __shared__ __align__(16) ushort tileT[64][68];
    const int t = threadIdx.x;
    if (blockIdx.x < 2048) {                        // K convert+swizzle
        const int u   = blockIdx.x * 256 + t;       // one 16B chunk/thread
        const int c   = u & 15;                     // d-chunk 0..15
        const int key = (u >> 4) & 1023;
        const int bh  = u >> 14;
        const int row = key & 127, kt = key >> 7;
        const int h   = kt * 2 + (c >> 3), c_lo = c & 7;
        const float* s = K + ((size_t)(bh * S_ + key)) * D_ + c * 8;
        float4 a = *(const float4*)s, b2 = *(const float4*)(s + 4);
        short8 o = cvt8(a, b2);
        *(short8*)(Kb + (((size_t)(bh * 16 + h) * 128 + row) * 8 +
                         (c_lo ^ (row & 7))) * 8) = o;
        return;
    }
    // V transpose: 1024 blocks = 32 bh x 16 kt(64 keys) x 2 dh(64 d)
    const int vb = blockIdx.x - 2048;
    const int bh = vb >> 5, r5 = vb & 31, kt = r5 >> 1, dh = r5 & 1;
    const float* src = V + ((size_t)(bh * S_ + kt * 64)) * D_ + dh * 64;
    #pragma unroll
    for (int i = 0; i < 4; ++i) {
        int idx = t + i * 256, r = idx >> 4, c = idx & 15;
        float4 vv = *(const float4*)(src + (size_t)r * D_ + c * 4);
        tileT[c * 4 + 0][r] = f2bf(vv.x);
        tileT[c * 4 + 1][r] = f2bf(vv.y);
        tileT[c * 4 + 2][r] = f2bf(vv.z);
        tileT[c * 4 + 3][r] = f2bf(vv.w);
    }
    __syncthreads();
    #pragma unroll
    for (int i = 0; i < 2; ++i) {
        int idx = t + i * 256, d = idx >> 3, jj = idx & 7;
        short8 val = *(const short8*)&tileT[d][jj * 8];
        *(short8*)(Vt + (((size_t)(bh * 16 + kt) * 128 + dh * 64 + d) * 8 +
                         (jj ^ (d & 7))) * 8) = val;
    }
}

// ---- main kernel --------------------------------------------------------
__global__ __launch_bounds__(512, 2)
void entmax_attn(const float* __restrict__ Q, const ushort* __restrict__ Kb,
                 const ushort* __restrict__ Vt, const int* __restrict__ M,
                 float* __restrict__ O)
{
    __shared__ __align__(16) ushort sc[16][1024];   // scores/P/cand overlay
    __shared__ __align__(16) ushort kv[3][128][64]; // rotating half-buffers

    const int t = threadIdx.x;
    const int w = t >> 6, lane = t & 63, l = lane & 15, quad = lane >> 4;
    const int bh = blockIdx.x >> 6, qt = blockIdx.x & 63, b = bh >> 3;

    const ushort* kb_h = Kb + (size_t)bh * (16 * 128 * 64);
    const ushort* vt_h = Vt + (size_t)bh * (16 * 128 * 64);

    const int n = w * 16 + l;                       // wave-private row
    const int chA = ((quad) ^ (l & 7)) * 8;         // swizzled frag chunks
    const int chB = ((4 + quad) ^ (l & 7)) * 8;

    // wave-private stage: wave w fills rows w*16..w*16+15 (2 x 1KB segs)
    auto stg = [&](int s, int buf) {
        const ushort* g = (s < 16 ? kb_h + (size_t)s * 8192
                                  : vt_h + (size_t)(s - 16) * 8192)
                          + w * 1024 + lane * 8;
        ushort* ld = &kv[buf][w * 16][0];           // HW adds lane*16 B
        gload16(g, ld);
        gload16(g + 512, ld + 512);
    };

    // ---- prologue: stages 0,1,2 in flight; Q direct (drains vmcnt) -----
    stg(0, 0); stg(1, 1); stg(2, 2);
    short8 aq[4];                                   // A[m=l][k=ks*32+quad*8+e]
    {
        const float* qr = Q + ((size_t)(bh * S_ + qt * 16 + l)) * D_ + quad * 8;
        #pragma unroll
        for (int ks = 0; ks < 4; ++ks) {
            float4 qa = *(const float4*)(qr + ks * 32);
            float4 qb = *(const float4*)(qr + ks * 32 + 4);
            aq[ks] = cvt8(qa, qb);
        }
    }

    // ---- phase 1: QK^T, stages 0..15, barrier-free ---------------------
    f32x4 acc = {0.f, 0.f, 0.f, 0.f};
    {
        int bufc = 0;
        #pragma unroll 1
        for (int s = 0; s < 16; ++s) {
            asm volatile("s_waitcnt vmcnt(4)" ::: "memory");
            short8 bk0 = *(const short8*)&kv[bufc][n][chA];
            short8 bk1 = *(const short8*)&kv[bufc][n][chB];
            const int dh = s & 1;
            if (dh == 0) { acc[0] = acc[1] = acc[2] = acc[3] = 0.f; }
            __builtin_amdgcn_s_setprio(1);
            acc = __builtin_amdgcn_mfma_f32_16x16x32_bf16(aq[dh * 2 + 0], bk0, acc, 0, 0, 0);
            acc = __builtin_amdgcn_mfma_f32_16x16x32_bf16(aq[dh * 2 + 1], bk1, acc, 0, 0, 0);
            __builtin_amdgcn_s_setprio(0);
            if (dh == 1) {                          // scaled scores -> sc
                const int coln = (s >> 1) * 16 + w * 2 + (l >> 3);
                #pragma unroll
                for (int r = 0; r < 4; ++r) {
                    const int rr = quad * 4 + r;
                    sc[rr][((coln ^ (rr & 7)) << 3) + (l & 7)] =
                        f2bf(acc[r] * SCALE_F);
                }
            }
            asm volatile("" ::: "memory");          // reads stay above DMA
            stg(s + 3, bufc);                       // stages 3..18 (16..18=V)
            bufc = (bufc == 2) ? 0 : bufc + 1;
        }
    }
    asm volatile("s_waitcnt lgkmcnt(0)" ::: "memory");
    __builtin_amdgcn_s_barrier();                   // all scores visible

    // ---- phase 2: regather + mask + max + normalize --------------------
    const int row = t >> 5, u = t & 31;             // 32 threads per row
    const int qg = qt * 16 + row;
    float x[32];
    #pragma unroll
    for (int c = 0; c < 4; ++c) {
        short8 v8 = *(const short8*)&sc[row][((c * 32 + u) ^ (row & 7)) << 3];
        #pragma unroll
        for (int e = 0; e < 8; ++e) x[c * 8 + e] = bf2f(((ushort*)&v8)[e]);
    }
    {   // mask: key = c*256 + u*8 + h*4 + e
        const int4* mrow = (const int4*)(M + ((size_t)b * S_ + qg) * S_);
        #pragma unroll
        for (int c = 0; c < 4; ++c) {
            #pragma unroll
            for (int h = 0; h < 2; ++h) {
                int4 mm = mrow[c * 64 + u * 2 + h];
                if (mm.x == 0) x[c * 8 + h * 4 + 0] = NEG_INF_F;
                if (mm.y == 0) x[c * 8 + h * 4 + 1] = NEG_INF_F;
                if (mm.z == 0) x[c * 8 + h * 4 + 2] = NEG_INF_F;
                if (mm.w == 0) x[c * 8 + h * 4 + 3] = NEG_INF_F;
            }
        }
    }
    float mx = -3.0e38f;
    #pragma unroll
    for (int j = 0; j < 32; ++j) mx = fmaxf(mx, x[j]);
    #pragma unroll
    for (int off = 1; off < 32; off <<= 1) mx = fmaxf(mx, __shfl_xor(mx, off));
    #pragma unroll
    for (int j = 0; j < 32; ++j) x[j] = (x[j] - mx) * 0.5f;   // x <= 0

    // ---- candidate compaction into own sc row (scores dead; lockstep) --
    float* cand = (float*)&sc[row][0];              // 512 f32 = the row
    const unsigned long long halfmask =
        (lane >= 32) ? 0xFFFFFFFF00000000ull : 0x00000000FFFFFFFFull;
    int cnt = 0;
    #pragma unroll
    for (int j = 0; j < 32; ++j) {
        const bool p = (x[j] > -1.0f);              // tau* >= -1
        unsigned long long bal = __ballot(p) & halfmask;
        if (p) {
            int pos = cnt + (int)__builtin_amdgcn_mbcnt_hi(
                (unsigned)(bal >> 32),
                __builtin_amdgcn_mbcnt_lo((unsigned)bal, 0));
            if (pos < CCAP) cand[pos] = x[j];
        }
        cnt += __popcll(bal);
    }

    // ---- tau bisection on f(tau)=sum max(0,x-tau)^2=1, root in [-1,0] --
    float tau;
    if (cnt <= CCAP) {                              // compact path (normal)
        float lo = -1.f, hi = 0.f;
        #pragma unroll 1
        for (int it = 0; it < NITER; ++it) {
            const float tm = 0.5f * (lo + hi);
            float f = 0.f;
            for (int j = u; j < cnt; j += 32) {
                float d = fmaxf(cand[j] - tm, 0.f);
                f = fmaf(d, d, f);
            }
            #pragma unroll
            for (int off = 1; off < 32; off <<= 1) f += __shfl_xor(f, off);
            const bool ge = (f >= 1.f);
            lo = ge ? tm : lo;
            hi = ge ? hi : tm;
        }
        tau = 0.5f * (lo + hi);
    } else {                                        // fallback: full solve
        float lo = -1.f, hi = 0.f;
        #pragma unroll 1
        for (int it = 0; it < NITER; ++it) {
            const float tm = 0.5f * (lo + hi);
            float f = 0.f;
            #pragma unroll
            for (int j = 0; j < 32; ++j) {
                float d = fmaxf(x[j] - tm, 0.f);
                f = fmaf(d, d, f);
            }
            #pragma unroll
            for (int off = 1; off < 32; off <<= 1) f += __shfl_xor(f, off);
            const bool ge = (f >= 1.f);
            lo = ge ? tm : lo;
            hi = ge ? hi : tm;
        }
        tau = 0.5f * (lo + hi);
    }

    // ---- y = max(0,x-tau)^2 back into sc (dense, swizzled) -------------
    #pragma unroll
    for (int c = 0; c < 4; ++c) {
        short8 v8;
        #pragma unroll
        for (int e = 0; e < 8; ++e) {
            float d = fmaxf(x[c * 8 + e] - tau, 0.f);
            ((ushort*)&v8)[e] = f2bf(d * d);
        }
        *(short8*)&sc[row][((c * 32 + u) ^ (row & 7)) << 3] = v8;
    }
    asm volatile("s_waitcnt lgkmcnt(0)" ::: "memory");
    __builtin_amdgcn_s_barrier();                   // all y visible

    // ---- phase 3: O = P @ V^T, stages 16..31, barrier-free -------------
    f32x4 oa = {0.f, 0.f, 0.f, 0.f};
    {
        int bufc = 1;                               // 16 % 3
        #pragma unroll 1
        for (int s = 16; s < 30; ++s) {
            asm volatile("s_waitcnt vmcnt(4)" ::: "memory");
            const int vh = s - 16;
            short8 bv0 = *(const short8*)&kv[bufc][n][chA];
            short8 bv1 = *(const short8*)&kv[bufc][n][chB];
            short8 ap0 = *(const short8*)&sc[l][((vh * 8 + quad) ^ (l & 7)) << 3];
            short8 ap1 = *(const short8*)&sc[l][((vh * 8 + 4 + quad) ^ (l & 7)) << 3];
            __builtin_amdgcn_s_setprio(1);
            oa = __builtin_amdgcn_mfma_f32_16x16x32_bf16(ap0, bv0, oa, 0, 0, 0);
            oa = __builtin_amdgcn_mfma_f32_16x16x32_bf16(ap1, bv1, oa, 0, 0, 0);
            __builtin_amdgcn_s_setprio(0);
            asm volatile("" ::: "memory");
            if (s < 29) stg(s + 3, bufc);           // stages 19..31
            bufc = (bufc == 2) ? 0 : bufc + 1;
        }
        {   // s = 30 (buf 0): only stage 31 may remain outstanding
            asm volatile("s_waitcnt vmcnt(2)" ::: "memory");
            short8 bv0 = *(const short8*)&kv[0][n][chA];
            short8 bv1 = *(const short8*)&kv[0][n][chB];
            short8 ap0 = *(const short8*)&sc[l][((14 * 8 + quad) ^ (l & 7)) << 3];
            short8 ap1 = *(const short8*)&sc[l][((14 * 8 + 4 + quad) ^ (l & 7)) << 3];
            oa = __builtin_amdgcn_mfma_f32_16x16x32_bf16(ap0, bv0, oa, 0, 0, 0);
            oa = __builtin_amdgcn_mfma_f32_16x16x32_bf16(ap1, bv1, oa, 0, 0, 0);
        }
        {   // s = 31 (buf 1): drain
            asm volatile("s_waitcnt vmcnt(0)" ::: "memory");
            short8 bv0 = *(const short8*)&kv[1][n][chA];
            short8 bv1 = *(const short8*)&kv[1][n][chB];
            short8 ap0 = *(const short8*)&sc[l][((15 * 8 + quad) ^ (l & 7)) << 3];
            short8 ap1 = *(const short8*)&sc[l][((15 * 8 + 4 + quad) ^ (l & 7)) << 3];
            oa = __builtin_amdgcn_mfma_f32_16x16x32_bf16(ap0, bv0, oa, 0, 0, 0);
            oa = __builtin_amdgcn_mfma_f32_16x16x32_bf16(ap1, bv1, oa, 0, 0, 0);
        }
    }

    // ---- epilogue: C/D map (col=d-within-slice=l, row=q=quad*4+r) ------
    float* ob = O + ((size_t)bh * S_ + (size_t)qt * 16) * D_;
    #pragma unroll
    for (int r = 0; r < 4; ++r)
        ob[(size_t)(quad * 4 + r) * D_ + w * 16 + l] = oa[r];
}

extern "C" void kernel_launch(void* const* d_in, const int* in_sizes, int n_in,
                              void* d_out, int out_size, void* d_ws, size_t ws_size,
                              hipStream_t stream) {
    const float* q = (const float*)d_in[0];
    const float* k = (const float*)d_in[1];
    const float* v = (const float*)d_in[2];
    const int*   m = (const int*)d_in[3];
    float*       o = (float*)d_out;

    ushort* Kb = (ushort*)d_ws;                      // 8,388,608 B
    ushort* Vt = (ushort*)((char*)d_ws + 8388608);   // 8,388,608 B

    pre_cvt<<<3072, 256, 0, stream>>>(k, v, Kb, Vt);
    entmax_attn<<<2048, 512, 0, stream>>>(q, Kb, Vt, m, o);
}